// Round 16
// baseline (266.224 us; speedup 1.0000x reference)
//
#include <hip/hip_runtime.h>

#define BATCH 16
#define TXT   320
#define NMELC 80
#define MELT  2000
#define PADM  1.0e12f
#define L2E   1.4426950408889634f
#define LN2   0.6931471805599453f
#define EPSL2 1.4426950e-7f

// ---------------------------------------------------------------------------
// Kernel A: log_prob[b,j,t] = s*(xx - 2xm + mm), s = -0.5/80 (verified r5-r15)
// ---------------------------------------------------------------------------
__global__ __launch_bounds__(256) void lp_kernel(
    const float* __restrict__ mlv,   // (B,320,160)
    const float* __restrict__ ms,    // (B,80,2000)
    float* __restrict__ out_lp)      // (B,320,2000)  (d_out+1)
{
    __shared__ float Gt[16][64];
    __shared__ float Ft[16][256];
    __shared__ float bias_s[64];
    __shared__ float bias_p[256];

    const int b   = blockIdx.z;
    const int j0  = blockIdx.y * 64;
    const int t0  = blockIdx.x * 256;
    const int tid = threadIdx.x;
    const float s = -0.00625f;

    const float* mlv_b = mlv + (size_t)b * TXT * 160;
    const float* ms_b  = ms  + (size_t)b * NMELC * MELT;

    {
        const int jj = tid >> 2;
        const int q  = tid & 3;
        const float* p = mlv_b + (size_t)(j0 + jj) * 160 + q * 20;
        float part = 0.f;
        #pragma unroll
        for (int c = 0; c < 20; ++c) {
            float mu = p[c];
            float lv = p[c + 80];
            float iv = __expf(-lv);
            part += mu * mu * iv + lv;
        }
        bias_p[tid] = part;
    }
    __syncthreads();
    if (tid < 64) {
        float v = bias_p[tid * 4] + bias_p[tid * 4 + 1] +
                  bias_p[tid * 4 + 2] + bias_p[tid * 4 + 3];
        bias_s[tid] = s * v;
    }

    float acc[8][8];
    #pragma unroll
    for (int i = 0; i < 8; ++i)
        #pragma unroll
        for (int k = 0; k < 8; ++k) acc[i][k] = 0.f;

    const int jg = tid >> 5;
    const int tg = tid & 31;

    for (int kc = 0; kc < 10; ++kc) {
        const int c0 = kc * 8;
        __syncthreads();
        #pragma unroll
        for (int i = 0; i < 2; ++i) {
            int f   = tid + i * 256;
            int cr  = f >> 6;
            int col = f & 63;
            float mu = mlv_b[(size_t)(j0 + col) * 160 + (c0 + cr)];
            float lv = mlv_b[(size_t)(j0 + col) * 160 + (80 + c0 + cr)];
            float iv = __expf(-lv);
            Gt[cr][col]     = s * iv;
            Gt[cr + 8][col] = -2.f * s * mu * iv;
        }
        #pragma unroll
        for (int i = 0; i < 2; ++i) {
            int f   = tid + i * 256;
            int row = f >> 6;
            int c4  = f & 63;
            int t   = t0 + c4 * 4;
            float4 v = (t + 3 < MELT)
                ? *(const float4*)&ms_b[(size_t)(c0 + row) * MELT + t]
                : make_float4(0.f, 0.f, 0.f, 0.f);
            *(float4*)&Ft[row][c4 * 4] =
                make_float4(v.x * v.x, v.y * v.y, v.z * v.z, v.w * v.w);
            *(float4*)&Ft[row + 8][c4 * 4] = v;
        }
        __syncthreads();
        #pragma unroll
        for (int k = 0; k < 16; ++k) {
            float4 g0 = *(const float4*)&Gt[k][jg * 8];
            float4 g1 = *(const float4*)&Gt[k][jg * 8 + 4];
            float4 f0 = *(const float4*)&Ft[k][tg * 8];
            float4 f1 = *(const float4*)&Ft[k][tg * 8 + 4];
            float ga[8] = {g0.x, g0.y, g0.z, g0.w, g1.x, g1.y, g1.z, g1.w};
            float fa[8] = {f0.x, f0.y, f0.z, f0.w, f1.x, f1.y, f1.z, f1.w};
            #pragma unroll
            for (int ji = 0; ji < 8; ++ji)
                #pragma unroll
                for (int ti = 0; ti < 8; ++ti)
                    acc[ji][ti] = fmaf(ga[ji], fa[ti], acc[ji][ti]);
        }
    }

    #pragma unroll
    for (int ji = 0; ji < 8; ++ji) {
        int j = j0 + jg * 8 + ji;
        float bs = bias_s[jg * 8 + ji];
        float* orow = out_lp + (size_t)(b * TXT + j) * MELT;
        #pragma unroll
        for (int ti = 0; ti < 8; ++ti) {
            int t = t0 + tg * 8 + ti;
            if (t < MELT) orow[t] = acc[ji][ti] + bs;
        }
    }
}

// ---------------------------------------------------------------------------
// dp_body<DIR,FULL>: compile-time-specialized half/full DP pass.
// Systolic skew, 2 j/lane, DPP wave_shr:1 neighbor, 2 LDS rings, 3-deep
// prefetch. DIR=1 = mirrored backward (rows 319-j', cols tend-s) with
// E-transform. Guarded 9-group prologue (bwd init protection), lean steady
// loop (r9 form), latched tail. No index clamps (range-proven valid).
// ---------------------------------------------------------------------------
__device__ __forceinline__ float dpp_shr1(float x) {
    return __int_as_float(__builtin_amdgcn_update_dpp(
        0, __float_as_int(x), 0x138 /*wave_shr:1*/, 0xF, 0xF, false));
}

template<int DIR, int FULL>
__device__ __forceinline__ void dp_body(
    const float* __restrict__ lp, int b, int tend, int tl,
    float* __restrict__ Fout, float* __restrict__ out0, float* SMEM)
{
    float (*bnd)[2080] = (float(*)[2080])SMEM;
    int* prog = (int*)(SMEM + 4160);

    const int tid = threadIdx.x;
    const int w   = tid >> 6;
    const int l   = tid & 63;
    const int tm    = tend >> 1;
    const int steps = FULL ? tend : (DIR ? tend - tm : tm);

    if (tid < 2) prog[tid] = 0;

    const int tc = tid < 160 ? tid : 159;
    const int R0 = DIR ? (319 - 2 * tc) : (2 * tc);
    const int R1 = DIR ? (318 - 2 * tc) : (2 * tc + 1);
    const float* r0 = lp + ((size_t)b * TXT + R0) * MELT;
    const float* r1 = lp + ((size_t)b * TXT + R1) * MELT;

    float A1 = -PADM, A2 = -PADM;
    if (!DIR) {
        if (tid == 0) A1 = lp[(size_t)b * TXT * MELT] * L2E;
    } else {
        const int jin = 320 - tl;
        const float vin =
            fmaf(lp[((size_t)b * TXT + (tl - 1)) * MELT + tend], L2E, EPSL2);
        if (tid == (jin >> 1)) { if (jin & 1) A2 = vin; else A1 = vin; }
    }
    float A1F = A1, A2F = A2;

    if (l == 63 && w < 2) bnd[w][0] = A2;
    __syncthreads();

    float ptA2 = -PADM;
    float ptB2 = dpp_shr1(A2);
    const bool is0     = (l == 0);
    const bool isPub   = (l == 63) && (w < 2);
    const bool hasRing = (w > 0);
    int seen = 0;
    const int imax = steps + 63;
    const int sEnd = steps - 23;

#define COLOF(S_) (DIR ? (tend - (S_)) : (S_))

    float PA[16], PB[16], PC[16];
    #pragma unroll
    for (int q = 0; q < 8; ++q) {
        int c_ = COLOF(1 + q - l);
        PA[2 * q] = r0[c_]; PA[2 * q + 1] = r1[c_];
    }
    #pragma unroll
    for (int q = 0; q < 8; ++q) {
        int c_ = COLOF(9 + q - l);
        PB[2 * q] = r0[c_]; PB[2 * q + 1] = r1[c_];
    }
    #pragma unroll
    for (int q = 0; q < 16; ++q) PA[q] = fmaf(PA[q], L2E, EPSL2);

#define RING_RD(BQ_, T0_)                                                    \
    {                                                                        \
        float4 q0_ = *(const float4*)&bnd[w - 1][T0_];                       \
        float4 q1_ = *(const float4*)&bnd[w - 1][(T0_) + 4];                 \
        BQ_[0]=q0_.x; BQ_[1]=q0_.y; BQ_[2]=q0_.z; BQ_[3]=q0_.w;              \
        BQ_[4]=q1_.x; BQ_[5]=q1_.y; BQ_[6]=q1_.z; BQ_[7]=q1_.w;              \
    }
#define RING_POLL(NEED_)                                                     \
    if (seen < (NEED_)) {                                                    \
        int tgt_ = (NEED_) + 32;                                             \
        if (tgt_ > steps - 1) tgt_ = steps - 1;                              \
        if (tgt_ < (NEED_)) tgt_ = (NEED_);                                  \
        volatile int* pv_ = &prog[w - 1];                                    \
        int v_ = *pv_;                                                       \
        while (v_ < tgt_) { __builtin_amdgcn_s_sleep(1); v_ = *pv_; }        \
        seen = v_;                                                           \
        __asm__ volatile("" ::: "memory");                                   \
    }

    float bqC[8];
    if (hasRing) {
        int n0 = 7; if (n0 > steps - 1) n0 = steps - 1;
        RING_POLL(n0)
        RING_RD(bqC, 0)
    } else {
        #pragma unroll
        for (int q = 0; q < 8; ++q) bqC[q] = -PADM;
    }

// core 2-j step; GUARD: hold state pre-start; LATCH: capture frontier
#define STEPX(Pc_, q_, AQ_, VT_, GUARD_, LATCH_)                             \
    {                                                                        \
        float pt_ = is0 ? bqC[q_] : ptA2;                                    \
        float m1_ = fmaxf(A1, pt_);                                          \
        float d1_ = A1 - pt_;                                                \
        float e1_ = __builtin_amdgcn_exp2f(-fabsf(d1_));                     \
        float g1_ = __builtin_amdgcn_logf(1.0f + e1_);                       \
        float n1_ = m1_ + g1_ + Pc_[2 * q_];                                 \
        float m2_ = fmaxf(A2, A1);                                           \
        float d2_ = A2 - A1;                                                 \
        float e2_ = __builtin_amdgcn_exp2f(-fabsf(d2_));                     \
        float g2_ = __builtin_amdgcn_logf(1.0f + e2_);                       \
        float n2_ = m2_ + g2_ + Pc_[2 * q_ + 1];                             \
        if (GUARD_) {                                                        \
            bool go_ = ((VT_) + q_ >= 1);                                    \
            A1 = go_ ? n1_ : A1;                                             \
            A2 = go_ ? n2_ : A2;                                             \
        } else { A1 = n1_; A2 = n2_; }                                       \
        float ns_ = dpp_shr1(A2);                                            \
        ptA2 = ptB2; ptB2 = ns_;                                             \
        AQ_ = A2;                                                            \
        if (LATCH_) {                                                        \
            bool c_ = ((VT_) + q_ == steps);                                 \
            A1F = c_ ? A1 : A1F;                                             \
            A2F = c_ ? A2 : A2F;                                             \
        }                                                                    \
    }

#define GROUPX(Pc_, Pm_, Pl_, I0_, GUARD_, LATCH_)                           \
{                                                                            \
    float bqN[8];                                                            \
    if (hasRing) {                                                           \
        int need_ = (I0_) + 14;                                              \
        if (need_ > steps - 1) need_ = steps - 1;                            \
        RING_POLL(need_)                                                     \
        int rb_ = (I0_) + 7; if (rb_ > 2048) rb_ = 2048;                     \
        RING_RD(bqN, rb_)                                                    \
    } else {                                                                 \
        _Pragma("unroll") for (int q_=0;q_<8;++q_) bqN[q_] = -PADM;          \
    }                                                                        \
    _Pragma("unroll") for (int q_=0;q_<8;++q_) {                             \
        int c_ = COLOF((I0_) + 16 + q_ - l);                                 \
        Pl_[2*q_] = r0[c_]; Pl_[2*q_+1] = r1[c_];                            \
    }                                                                        \
    float aq2[8];                                                            \
    const int vt_ = (I0_) - l;                                               \
    _Pragma("unroll") for (int q_=0;q_<8;++q_)                               \
        STEPX(Pc_, q_, aq2[q_], vt_, GUARD_, LATCH_)                         \
    if (isPub) {                                                             \
        const int t63_ = (I0_) - 63;                                         \
        if (GUARD_) {                                                        \
            _Pragma("unroll") for (int q_=0;q_<8;++q_) {                     \
                int tq_ = t63_ + q_;                                         \
                if (tq_ >= 1) bnd[w][tq_] = aq2[q_];                         \
            }                                                                \
        } else {                                                             \
            _Pragma("unroll") for (int q_=0;q_<8;++q_)                       \
                bnd[w][t63_ + q_] = aq2[q_];                                 \
        }                                                                    \
        __asm__ volatile("" ::: "memory");                                   \
        int pgv_ = t63_ + 7;                                                 \
        if (pgv_ > steps - 1) pgv_ = steps - 1;                              \
        if (pgv_ >= 1) prog[w] = pgv_;                                       \
    }                                                                        \
    _Pragma("unroll") for (int q_=0;q_<16;++q_)                              \
        Pm_[q_] = fmaf(Pm_[q_], L2E, EPSL2);                                 \
    _Pragma("unroll") for (int q_=0;q_<8;++q_) bqC[q_] = bqN[q_];            \
}

    // guarded prologue: 9 groups (i0 = 1..65), rotation returns to (A,B,C)
    GROUPX(PA, PB, PC, 1,  1, 0)
    GROUPX(PB, PC, PA, 9,  1, 0)
    GROUPX(PC, PA, PB, 17, 1, 0)
    GROUPX(PA, PB, PC, 25, 1, 0)
    GROUPX(PB, PC, PA, 33, 1, 0)
    GROUPX(PC, PA, PB, 41, 1, 0)
    GROUPX(PA, PB, PC, 49, 1, 0)
    GROUPX(PB, PC, PA, 57, 1, 0)
    GROUPX(PC, PA, PB, 65, 1, 0)

    int i0 = 73;
    int ph = 0;
    while (i0 <= sEnd) {
        GROUPX(PA, PB, PC, i0, 0, 0) i0 += 8;
        if (i0 > sEnd) { ph = 1; break; }
        GROUPX(PB, PC, PA, i0, 0, 0) i0 += 8;
        if (i0 > sEnd) { ph = 2; break; }
        GROUPX(PC, PA, PB, i0, 0, 0) i0 += 8;
    }
    if (ph == 1) {
        #pragma unroll
        for (int q = 0; q < 16; ++q) {
            float tmp = PA[q]; PA[q] = PB[q]; PB[q] = PC[q]; PC[q] = tmp;
        }
    } else if (ph == 2) {
        #pragma unroll
        for (int q = 0; q < 16; ++q) {
            float tmp = PA[q]; PA[q] = PC[q]; PC[q] = PB[q]; PB[q] = tmp;
        }
    }
    while (i0 <= imax) {
        GROUPX(PA, PB, PC, i0, 0, 1) i0 += 8;
        if (i0 > imax) break;
        GROUPX(PB, PC, PA, i0, 0, 1) i0 += 8;
        if (i0 > imax) break;
        GROUPX(PC, PA, PB, i0, 0, 1) i0 += 8;
    }

#undef GROUPX
#undef STEPX
#undef RING_RD
#undef RING_POLL
#undef COLOF

    if (FULL) {
        if (tid == ((tl - 1) >> 1)) {
            float Af = ((tl - 1) & 1) ? A2F : A1F;
            atomicAdd(out0, -(Af * LN2 / (float)(tend + 1)) / (float)BATCH);
        }
        return;
    }
    if (tid < 160) {
        if (!DIR) {
            *(float2*)&Fout[(size_t)b * TXT + 2 * tid] =
                make_float2(A1F, A2F);
        } else {
            float q0 = fmaf(r0[tm], L2E, EPSL2);
            float q1 = fmaf(r1[tm], L2E, EPSL2);
            *(float2*)&Fout[(size_t)b * TXT + (318 - 2 * tid)] =
                make_float2(A2F - q1, A1F - q0);
        }
    }
}

// ---------------------------------------------------------------------------
__global__ __launch_bounds__(192, 1) void dp2_kernel(
    const float* __restrict__ lp, const int* __restrict__ tlen,
    const int* __restrict__ mlen, float* __restrict__ F,
    float* __restrict__ G)
{
    __shared__ float SM[4164];
    const int blk = blockIdx.x;
    const int b   = blk & 15;
    const int tend = mlen[b] - 1;
    const int tl   = tlen[b];
    if (blk < 16) dp_body<0, 0>(lp, b, tend, tl, F, nullptr, SM);
    else          dp_body<1, 0>(lp, b, tend, tl, G, nullptr, SM);
}

__global__ __launch_bounds__(192, 1) void dp_fb_kernel(
    const float* __restrict__ lp, const int* __restrict__ tlen,
    const int* __restrict__ mlen, float* __restrict__ out0)
{
    __shared__ float SM[4164];
    const int b = blockIdx.x;
    dp_body<0, 1>(lp, b, mlen[b] - 1, tlen[b], nullptr, out0, SM);
}

// join: res[b] = lse_j(F+G) * LN2 / ml
__global__ void fin1_kernel(const float* __restrict__ F,
                            const float* __restrict__ G,
                            const int* __restrict__ mlen,
                            float* __restrict__ res)
{
    const int b = blockIdx.x;
    const int l = threadIdx.x;
    float v[5];
    float m = -3.0e38f;
    #pragma unroll
    for (int k = 0; k < 5; ++k) {
        int j = 5 * l + k;
        v[k] = F[(size_t)b * TXT + j] + G[(size_t)b * TXT + j];
        m = fmaxf(m, v[k]);
    }
    #pragma unroll
    for (int o = 32; o; o >>= 1) m = fmaxf(m, __shfl_xor(m, o));
    float s = 0.f;
    #pragma unroll
    for (int k = 0; k < 5; ++k) {
        float d = v[k] - m;
        d = d < -120.f ? -120.f : d;
        s += __builtin_amdgcn_exp2f(d);
    }
    #pragma unroll
    for (int o = 32; o; o >>= 1) s += __shfl_xor(s, o);
    if (l == 0)
        res[b] = (m + __builtin_amdgcn_logf(s)) * LN2 / (float)mlen[b];
}

__global__ void fin2_kernel(const float* __restrict__ res, float* __restrict__ out0)
{
    int l = threadIdx.x;
    float v = (l < BATCH) ? res[l] : 0.f;
    #pragma unroll
    for (int off = 32; off; off >>= 1) v += __shfl_down(v, off);
    if (l == 0) out0[0] = -(v / (float)BATCH);
}

__global__ void zero1_kernel(float* out0) { out0[0] = 0.f; }

// ---------------------------------------------------------------------------
extern "C" void kernel_launch(void* const* d_in, const int* in_sizes, int n_in,
                              void* d_out, int out_size, void* d_ws, size_t ws_size,
                              hipStream_t stream)
{
    const float* mlv = (const float*)d_in[0];
    const float* ms  = (const float*)d_in[1];
    const int*   tl  = (const int*)d_in[2];
    const int*   ml  = (const int*)d_in[3];
    float* out    = (float*)d_out;
    float* out_lp = out + 1;

    const size_t need = 256 + (size_t)2 * BATCH * TXT * sizeof(float);
    bool ok = ws_size >= need;
    float* res = (float*)d_ws;                    // 16 floats
    float* F   = (float*)((char*)d_ws + 256);     // 16*320
    float* G   = F + (size_t)BATCH * TXT;         // 16*320

    dim3 gA(8, 5, 16);
    lp_kernel<<<gA, 256, 0, stream>>>(mlv, ms, out_lp);

    if (ok) {
        dp2_kernel<<<32, 192, 0, stream>>>(out_lp, tl, ml, F, G);
        fin1_kernel<<<BATCH, 64, 0, stream>>>(F, G, ml, res);
        fin2_kernel<<<1, 64, 0, stream>>>(res, out);
    } else {
        zero1_kernel<<<1, 1, 0, stream>>>(out);
        dp_fb_kernel<<<BATCH, 192, 0, stream>>>(out_lp, tl, ml, out);
    }
}

// Round 17
// 208.545 us; speedup vs baseline: 1.2766x; 1.2766x over previous
//
#include <hip/hip_runtime.h>

#define BATCH 16
#define TXT   320
#define NMELC 80
#define MELT  2000
#define PADM  1.0e12f
#define L2E   1.4426950408889634f
#define LN2   0.6931471805599453f
#define EPSL2 1.4426950e-7f

typedef __attribute__((ext_vector_type(8))) short bf16x8;
typedef __attribute__((ext_vector_type(4))) float f32x4;

__device__ __forceinline__ short f2bf(float x) {
    unsigned u = __float_as_uint(x);
    unsigned r = (u + 0x7FFFu + ((u >> 16) & 1u)) >> 16;
    return (short)r;
}

// ---------------------------------------------------------------------------
// Kernel A (MFMA): lp[b,j,t] = sum_k G[j,k]*F[k,t] + bias[j], K=160.
//   k <  80: G = s*ivar,          F = x^2
//   k >= 80: G = -2*s*mu*ivar,    F = x        (s = -0.5/80)
// Block: 64j x 128t, 256 thr (4 waves, wave w = j-rows w*16..w*16+15).
// A/B staged once in LDS as bf16, k-packed [kb][x][8] so each lane's MFMA
// fragment is one contiguous ds_read_b128. mfma_f32_16x16x32_bf16, 5 K-steps.
// C/D layout (HW-verified): col = lane&15, row = (lane>>4)*4 + reg.
// ---------------------------------------------------------------------------
__global__ __launch_bounds__(256) void lp_kernel(
    const float* __restrict__ mlv,   // (B,320,160)
    const float* __restrict__ ms,    // (B,80,2000)
    float* __restrict__ out_lp)      // (B,320,2000)  (d_out+1)
{
    __shared__ short Ash[20][64][8];    // A[kb][jloc][ke]  20.5 KB
    __shared__ short Bsh[20][128][8];   // B[kb][tloc][ke]  41 KB
    __shared__ float bias_p[256];
    __shared__ float bias_s[64];

    const int b   = blockIdx.z;
    const int j0  = blockIdx.y * 64;
    const int t0  = blockIdx.x * 128;
    const int tid = threadIdx.x;
    const float s = -0.00625f;

    const float* mlv_b = mlv + (size_t)b * TXT * 160;
    const float* ms_b  = ms  + (size_t)b * NMELC * MELT;

    // bias: 4 threads per j, 20 c-terms each (verified r5-r16)
    {
        const int jj = tid >> 2;
        const int q  = tid & 3;
        const float* p = mlv_b + (size_t)(j0 + jj) * 160 + q * 20;
        float part = 0.f;
        #pragma unroll
        for (int c = 0; c < 20; ++c) {
            float mu = p[c];
            float lv = p[c + 80];
            float iv = __expf(-lv);
            part += mu * mu * iv + lv;
        }
        bias_p[tid] = part;
    }
    __syncthreads();
    if (tid < 64) {
        float v = bias_p[tid * 4] + bias_p[tid * 4 + 1] +
                  bias_p[tid * 4 + 2] + bias_p[tid * 4 + 3];
        bias_s[tid] = s * v;
    }

    // A staging: 64j x 80c pairs -> two bf16 rows of A
    #pragma unroll
    for (int pass = 0; pass < 20; ++pass) {
        int idx = pass * 256 + tid;
        int j = idx / 80;            // 0..63
        int c = idx - j * 80;        // 0..79
        float mu = mlv_b[(size_t)(j0 + j) * 160 + c];
        float lv = mlv_b[(size_t)(j0 + j) * 160 + 80 + c];
        float iv = __expf(-lv);
        Ash[c >> 3][j][c & 7]        = f2bf(s * iv);
        Ash[10 + (c >> 3)][j][c & 7] = f2bf(-2.f * s * mu * iv);
    }
    // B staging: 80c x 128t (x^2 and x rows)
    #pragma unroll
    for (int pass = 0; pass < 10; ++pass) {
        int c   = pass * 8 + (tid >> 5);   // 0..79
        int t4i = tid & 31;
        int t   = t0 + t4i * 4;
        float xv[4];
        if (t + 3 < MELT) {
            float4 v = *(const float4*)&ms_b[(size_t)c * MELT + t];
            xv[0] = v.x; xv[1] = v.y; xv[2] = v.z; xv[3] = v.w;
        } else {
            #pragma unroll
            for (int i = 0; i < 4; ++i)
                xv[i] = (t + i < MELT) ? ms_b[(size_t)c * MELT + t + i] : 0.f;
        }
        #pragma unroll
        for (int i = 0; i < 4; ++i) {
            Bsh[c >> 3][t4i * 4 + i][c & 7]        = f2bf(xv[i] * xv[i]);
            Bsh[10 + (c >> 3)][t4i * 4 + i][c & 7] = f2bf(xv[i]);
        }
    }
    __syncthreads();

    const int wv = tid >> 6;
    const int l  = tid & 63;
    const int lr = l & 15;     // A-row / B-col / D-col within fragment
    const int lg = l >> 4;     // k-group (0..3)

    f32x4 acc[8];
    #pragma unroll
    for (int f = 0; f < 8; ++f) acc[f] = (f32x4){0.f, 0.f, 0.f, 0.f};

    #pragma unroll
    for (int ks = 0; ks < 5; ++ks) {
        const int kb = ks * 4 + lg;
        bf16x8 a = *(const bf16x8*)&Ash[kb][wv * 16 + lr][0];
        #pragma unroll
        for (int f = 0; f < 8; ++f) {
            bf16x8 bb = *(const bf16x8*)&Bsh[kb][f * 16 + lr][0];
            acc[f] = __builtin_amdgcn_mfma_f32_16x16x32_bf16(a, bb, acc[f],
                                                             0, 0, 0);
        }
    }

    float bs[4];
    #pragma unroll
    for (int r = 0; r < 4; ++r) bs[r] = bias_s[wv * 16 + lg * 4 + r];
    #pragma unroll
    for (int f = 0; f < 8; ++f) {
        int t = t0 + f * 16 + lr;
        if (t < MELT) {
            #pragma unroll
            for (int r = 0; r < 4; ++r) {
                int j = j0 + wv * 16 + lg * 4 + r;
                out_lp[((size_t)b * TXT + j) * MELT + t] = acc[f][r] + bs[r];
            }
        }
    }
}

// ---------------------------------------------------------------------------
// Kernel B: forward DP — VERBATIM r9 winner (160 us). 2 j/lane, systolic
// skew i = t + l, DPP wave_shr:1 neighbor, 3 waves + 2 LDS rings, 3-deep
// prefetch of out_lp rows.
// ---------------------------------------------------------------------------
__device__ __forceinline__ float dpp_shr1(float x) {
    return __int_as_float(__builtin_amdgcn_update_dpp(
        0, __float_as_int(x), 0x138 /*wave_shr:1*/, 0xF, 0xF, false));
}

__global__ __launch_bounds__(192, 1) void dp_kernel(
    const float* __restrict__ lp,    // (B,320,2000) = out_lp
    const int* __restrict__ tlen,
    const int* __restrict__ mlen,
    float* __restrict__ res,
    float* __restrict__ out0)
{
    __shared__ float bnd[2][2056];
    __shared__ int   prog[2];

    const int b    = blockIdx.x;
    const int tid  = threadIdx.x;
    const int w    = tid >> 6;
    const int l    = tid & 63;
    const int tend = mlen[b] - 1;
    const int tl   = tlen[b];

    if (tid < 2) prog[tid] = 0;

    int j0c = 2 * tid; if (j0c > 318) j0c = 318;   // clamp unused lanes
    const float* r0 = lp + (size_t)(b * TXT + j0c) * MELT;
    const float* r1 = r0 + MELT;

    float A1 = (tid == 0) ? lp[(size_t)b * TXT * MELT] * L2E : -PADM;
    float A2 = -PADM;
    float A1F = A1, A2F = A2;

    if (l == 63 && w < 2) bnd[w][0] = -PADM;
    __syncthreads();

    if (w == 2 && tl < 257) return;   // wave 2 unused

    float ptA2 = -PADM, ptB2 = -PADM;
    const bool is0     = (l == 0);
    const bool isPub   = (l == 63) && (w < 2);
    const bool hasRing = (w > 0);
    int seen = 0;

    const int imax = tend + 63;

    float PA[16], PB[16], PC[16];
    #pragma unroll
    for (int q = 0; q < 8; ++q) { PA[2*q] = r0[1 + q - l]; PA[2*q+1] = r1[1 + q - l]; }
    #pragma unroll
    for (int q = 0; q < 8; ++q) { PB[2*q] = r0[9 + q - l]; PB[2*q+1] = r1[9 + q - l]; }
    #pragma unroll
    for (int q = 0; q < 16; ++q) PA[q] = fmaf(PA[q], L2E, EPSL2);

    const float* p0 = r0 + 17 - l;
    const float* p1 = r1 + 17 - l;

#define RING_RD(BQ_, T0_)                                                    \
    {                                                                        \
        float4 q0_ = *(const float4*)&bnd[w - 1][T0_];                       \
        float4 q1_ = *(const float4*)&bnd[w - 1][(T0_) + 4];                 \
        BQ_[0]=q0_.x; BQ_[1]=q0_.y; BQ_[2]=q0_.z; BQ_[3]=q0_.w;              \
        BQ_[4]=q1_.x; BQ_[5]=q1_.y; BQ_[6]=q1_.z; BQ_[7]=q1_.w;              \
    }
#define RING_POLL(NEED_)                                                     \
    if (seen < (NEED_)) {                                                    \
        int tgt_ = (NEED_) + 32;                                             \
        if (tgt_ > tend - 1) tgt_ = tend - 1;                                \
        if (tgt_ < (NEED_)) tgt_ = (NEED_);                                  \
        volatile int* pv_ = &prog[w - 1];                                    \
        int v_ = *pv_;                                                       \
        while (v_ < tgt_) { __builtin_amdgcn_s_sleep(1); v_ = *pv_; }        \
        seen = v_;                                                           \
        __asm__ volatile("" ::: "memory");                                   \
    }

    float bqC[8];
    if (hasRing) {
        RING_POLL(7)
        RING_RD(bqC, 0)
    } else {
        #pragma unroll
        for (int q = 0; q < 8; ++q) bqC[q] = -PADM;
    }

#define STEP2(Pc_, q_, AQ_)                                                  \
    {                                                                        \
        float pt_ = is0 ? bqC[q_] : ptA2;                                    \
        float m1_ = fmaxf(A1, pt_);                                          \
        float d1_ = A1 - pt_;                                                \
        float e1_ = __builtin_amdgcn_exp2f(-fabsf(d1_));                     \
        float g1_ = __builtin_amdgcn_logf(1.0f + e1_);                       \
        float n1_ = m1_ + g1_ + Pc_[2 * q_];                                 \
        float m2_ = fmaxf(A2, A1);                                           \
        float d2_ = A2 - A1;                                                 \
        float e2_ = __builtin_amdgcn_exp2f(-fabsf(d2_));                     \
        float g2_ = __builtin_amdgcn_logf(1.0f + e2_);                       \
        float n2_ = m2_ + g2_ + Pc_[2 * q_ + 1];                             \
        float ns_ = dpp_shr1(n2_);                                           \
        ptA2 = ptB2; ptB2 = ns_;                                             \
        A1 = n1_; A2 = n2_; AQ_ = n2_;                                       \
    }

#define GROUP2_S(Pc_, Pm_, Pl_, I0_)                                         \
{                                                                            \
    float bqN[8];                                                            \
    if (hasRing) {                                                           \
        const int nt0_ = (I0_) + 7;                                          \
        RING_POLL(nt0_ + 7)                                                  \
        RING_RD(bqN, nt0_)                                                   \
    } else {                                                                 \
        _Pragma("unroll") for (int q_=0;q_<8;++q_) bqN[q_] = -PADM;          \
    }                                                                        \
    _Pragma("unroll") for (int q_=0;q_<8;++q_) {                             \
        Pl_[2*q_] = p0[q_]; Pl_[2*q_+1] = p1[q_];                            \
    }                                                                        \
    float aq2[8];                                                            \
    _Pragma("unroll")                                                        \
    for (int q_=0;q_<8;++q_) STEP2(Pc_, q_, aq2[q_])                         \
    if (isPub) {                                                             \
        const int t63_ = (I0_) - 63;                                         \
        if (t63_ >= 1) {                                                     \
            _Pragma("unroll") for (int q_=0;q_<8;++q_)                       \
                bnd[w][t63_ + q_] = aq2[q_];                                 \
        } else {                                                             \
            _Pragma("unroll") for (int q_=0;q_<8;++q_)                       \
                if (t63_ + q_ >= 1) bnd[w][t63_ + q_] = aq2[q_];             \
        }                                                                    \
        __asm__ volatile("" ::: "memory");  /* DS pipe is in-order */        \
        int pgv_ = t63_ + 7;                                                 \
        if (pgv_ >= 1) prog[w] = pgv_;                                       \
    }                                                                        \
    p0 += 8; p1 += 8;                                                        \
    _Pragma("unroll") for (int q_=0;q_<16;++q_)                              \
        Pm_[q_] = fmaf(Pm_[q_], L2E, EPSL2);                                 \
    _Pragma("unroll") for (int q_=0;q_<8;++q_) bqC[q_] = bqN[q_];            \
}

#define GROUP2_T(Pc_, Pm_, Pl_, I0_)                                         \
{                                                                            \
    float bqN[8];                                                            \
    if (hasRing) {                                                           \
        const int nt0_ = (I0_) + 7;                                          \
        int need_ = nt0_ + 7; if (need_ > tend - 1) need_ = tend - 1;        \
        RING_POLL(need_)                                                     \
        const int rb_ = nt0_ > 2048 ? 2048 : nt0_;                           \
        RING_RD(bqN, rb_)                                                    \
    } else {                                                                 \
        _Pragma("unroll") for (int q_=0;q_<8;++q_) bqN[q_] = -PADM;          \
    }                                                                        \
    _Pragma("unroll") for (int q_=0;q_<8;++q_) {                             \
        int t_ = (I0_) + 16 + q_ - l;                                        \
        t_ = t_ < 0 ? 0 : (t_ > tend ? tend : t_);                           \
        Pl_[2*q_] = r0[t_]; Pl_[2*q_+1] = r1[t_];                            \
    }                                                                        \
    float aq2[8];                                                            \
    const int vt_ = (I0_) - l;                                               \
    _Pragma("unroll")                                                        \
    for (int q_=0;q_<8;++q_) {                                               \
        STEP2(Pc_, q_, aq2[q_])                                              \
        bool c_ = (vt_ + q_ == tend);                                        \
        A1F = c_ ? A1 : A1F;                                                 \
        A2F = c_ ? A2 : A2F;                                                 \
    }                                                                        \
    if (isPub) {                                                             \
        const int t63_ = (I0_) - 63;                                         \
        _Pragma("unroll") for (int q_=0;q_<8;++q_) {                         \
            int tq_ = t63_ + q_;                                             \
            if (tq_ >= 1 && tq_ <= tend) bnd[w][tq_] = aq2[q_];              \
        }                                                                    \
        __asm__ volatile("" ::: "memory");                                   \
        int pgv_ = t63_ + 7; if (pgv_ > tend) pgv_ = tend;                   \
        if (pgv_ >= 1) prog[w] = pgv_;                                       \
    }                                                                        \
    _Pragma("unroll") for (int q_=0;q_<16;++q_)                              \
        Pm_[q_] = fmaf(Pm_[q_], L2E, EPSL2);                                 \
    _Pragma("unroll") for (int q_=0;q_<8;++q_) bqC[q_] = bqN[q_];            \
}

    int i0 = 1;
    const int sEnd = tend - 23;   // steady: loads in-bounds, latch can't fire
    int ph = 0;
    while (i0 <= sEnd) {
        GROUP2_S(PA, PB, PC, i0); i0 += 8;
        if (i0 > sEnd) { ph = 1; break; }
        GROUP2_S(PB, PC, PA, i0); i0 += 8;
        if (i0 > sEnd) { ph = 2; break; }
        GROUP2_S(PC, PA, PB, i0); i0 += 8;
    }
    if (ph == 1) {
        #pragma unroll
        for (int q = 0; q < 16; ++q) {
            float tmp = PA[q]; PA[q] = PB[q]; PB[q] = PC[q]; PC[q] = tmp;
        }
    } else if (ph == 2) {
        #pragma unroll
        for (int q = 0; q < 16; ++q) {
            float tmp = PA[q]; PA[q] = PC[q]; PC[q] = PB[q]; PB[q] = tmp;
        }
    }
    while (i0 <= imax) {
        GROUP2_T(PA, PB, PC, i0); i0 += 8;
        if (i0 > imax) break;
        GROUP2_T(PB, PC, PA, i0); i0 += 8;
        if (i0 > imax) break;
        GROUP2_T(PC, PA, PB, i0); i0 += 8;
    }

#undef GROUP2_S
#undef GROUP2_T
#undef STEP2
#undef RING_RD
#undef RING_POLL

    if (tid == ((tl - 1) >> 1)) {
        float Af = ((tl - 1) & 1) ? A2F : A1F;
        float v = Af * LN2 / (float)(tend + 1);
        if (res) res[b] = v;
        else     atomicAdd(out0, -v / (float)BATCH);
    }
}

__global__ void zero1_kernel(float* out0) { out0[0] = 0.f; }

__global__ void fin_kernel(const float* __restrict__ res, float* __restrict__ out0)
{
    int l = threadIdx.x;
    float v = (l < BATCH) ? res[l] : 0.f;
    #pragma unroll
    for (int off = 32; off; off >>= 1) v += __shfl_down(v, off);
    if (l == 0) out0[0] = -(v / (float)BATCH);
}

// ---------------------------------------------------------------------------
extern "C" void kernel_launch(void* const* d_in, const int* in_sizes, int n_in,
                              void* d_out, int out_size, void* d_ws, size_t ws_size,
                              hipStream_t stream)
{
    const float* mlv = (const float*)d_in[0];
    const float* ms  = (const float*)d_in[1];
    const int*   tl  = (const int*)d_in[2];
    const int*   ml  = (const int*)d_in[3];
    float* out    = (float*)d_out;
    float* out_lp = out + 1;

    bool res_ok = ws_size >= 64;
    float* res = res_ok ? (float*)d_ws : nullptr;

    dim3 gA(16, 5, 16);   // t-tiles(128), j-tiles(64), batch
    lp_kernel<<<gA, 256, 0, stream>>>(mlv, ms, out_lp);

    if (!res_ok) zero1_kernel<<<1, 1, 0, stream>>>(out);
    dp_kernel<<<BATCH, 192, 0, stream>>>(out_lp, tl, ml, res, out);
    if (res_ok) fin_kernel<<<1, 64, 0, stream>>>(res, out);
}